// Round 11
// baseline (680.990 us; speedup 1.0000x reference)
//
#include <hip/hip_runtime.h>
#include <hip/hip_bf16.h>

// Problem constants (B=4, L=1024, D=512, H=8, E=64, DIN=1024, N=16, K=4, R=32)
#define BB 4
#define LL 1024
#define DD 512
#define HH 8
#define EE 64
#define DIN 1024
#define NN 16
#define KK 4
#define RR 32
#define BL (BB*LL)   // 4096 rows
#define CC 32        // scan chunks (32 -> LC=32, 2048 waves in p1/p3)
#define LC (LL/CC)   // 32 steps per chunk
#define BDN (BB*DIN*NN)   // 65536 independent recurrences

using bf16 = __hip_bfloat16;
typedef __attribute__((ext_vector_type(8))) short short8;   // 8 bf16 = 4 VGPRs
typedef __attribute__((ext_vector_type(4))) float f32x4;

__device__ __forceinline__ float ldf(const float* p) { return *p; }
__device__ __forceinline__ float ldf(const bf16* p) { return __bfloat162float(*p); }
__device__ __forceinline__ void stf(float* p, float v) { *p = v; }
__device__ __forceinline__ void stf(bf16* p, float v) { *p = __float2bfloat16(v); }

// ---------------------------------------------------------------------------
// Batched weight transpose + f32->bf16 convert tail, one launch.
// ---------------------------------------------------------------------------
struct TpwJob { const float* in; bf16* out; int Kd, Nd, gx, tile0; };
struct TpwJobs { TpwJob j[7]; };

__global__ void tpw_batch_k(TpwJobs jobs, int tile_total,
                            const float* __restrict__ cvt_in,
                            bf16* __restrict__ cvt_out, int cvt_n)
{
    const int tile = blockIdx.x;
    if (tile >= tile_total) {
        int i = (tile - tile_total) * 256 + threadIdx.x;
        if (i < cvt_n) cvt_out[i] = __float2bfloat16(cvt_in[i]);
        return;
    }
    int ji = 0;
#pragma unroll
    for (int i = 1; i < 7; ++i) if (tile >= jobs.j[i].tile0) ji = i;
    const TpwJob jb = jobs.j[ji];
    const int lt = tile - jb.tile0;
    const int n0 = (lt % jb.gx) * 32;
    const int k0 = (lt / jb.gx) * 32;

    __shared__ float t[32][33];
    const int tx = threadIdx.x & 31, ty = threadIdx.x >> 5;
#pragma unroll
    for (int i = 0; i < 4; ++i)
        t[ty + 8 * i][tx] = jb.in[(size_t)(k0 + ty + 8 * i) * jb.Nd + n0 + tx];
    __syncthreads();
#pragma unroll
    for (int i = 0; i < 4; ++i)
        jb.out[(size_t)(n0 + ty + 8 * i) * jb.Kd + k0 + tx] = __float2bfloat16(t[tx][ty + 8 * i]);
}

// ---------------------------------------------------------------------------
// V transpose per head: vT[bh][e][l] = v[b][l][h*64+e]
// ---------------------------------------------------------------------------
__global__ void tpv_k(const bf16* __restrict__ v, bf16* __restrict__ vT)
{
    __shared__ float t[32][33];
    const int l0 = blockIdx.x * 32;
    const int e0 = blockIdx.y * 32;
    const int bh = blockIdx.z, b = bh >> 3, h = bh & 7;
    const int tx = threadIdx.x & 31, ty = threadIdx.x >> 5;
#pragma unroll
    for (int i = 0; i < 4; ++i)
        t[ty + 8 * i][tx] = ldf(&v[(size_t)(b * LL + l0 + ty + 8 * i) * DD + h * EE + e0 + tx]);
    __syncthreads();
#pragma unroll
    for (int i = 0; i < 4; ++i)
        stf(&vT[(size_t)(bh * EE + e0 + ty + 8 * i) * LL + l0 + tx], t[tx][ty + 8 * i]);
}

// ---------------------------------------------------------------------------
// Big MFMA GEMM: 128x128 block tile, 4 waves 2x2, 64x64 per wave (acc[4][4]).
// Optional z-batching. Grid (N/128, M/128, nz).
// ---------------------------------------------------------------------------
template <typename TC>
__global__ void mfma_gemm128_k(const bf16* __restrict__ A, int lda,
                               const bf16* __restrict__ Bt0, size_t bstride, int ldb,
                               const float* __restrict__ bias0,
                               const float* __restrict__ bias1,
                               const float* __restrict__ bias2,
                               TC* __restrict__ C0, size_t cstride, int ldc, int Kd)
{
    const int z = blockIdx.z;
    const bf16* Bt = Bt0 + (size_t)z * bstride;
    TC* C = C0 + (size_t)z * cstride;
    const float* bias = (z == 0) ? bias0 : (z == 1) ? bias1 : bias2;

    const int lane = threadIdx.x & 63;
    const int w = threadIdx.x >> 6;
    const int m = lane & 15, quad = lane >> 4;
    const int m0 = blockIdx.y * 128 + (w >> 1) * 64;
    const int n0 = blockIdx.x * 128 + (w & 1) * 64;

    f32x4 acc[4][4] = {};
    const bf16* ap = A + (size_t)(m0 + m) * lda + quad * 8;
    const bf16* bp = Bt + (size_t)(n0 + m) * ldb + quad * 8;
    const size_t rsa = (size_t)16 * lda;
    const size_t rsb = (size_t)16 * ldb;
    for (int k = 0; k < Kd; k += 32) {
        short8 a[4], b[4];
#pragma unroll
        for (int i = 0; i < 4; ++i) a[i] = *(const short8*)(ap + i * rsa + k);
#pragma unroll
        for (int j = 0; j < 4; ++j) b[j] = *(const short8*)(bp + j * rsb + k);
#pragma unroll
        for (int i = 0; i < 4; ++i)
#pragma unroll
            for (int j = 0; j < 4; ++j)
                acc[i][j] = __builtin_amdgcn_mfma_f32_16x16x32_bf16(a[i], b[j], acc[i][j], 0, 0, 0);
    }
    float bv[4];
#pragma unroll
    for (int j = 0; j < 4; ++j) bv[j] = bias ? bias[n0 + j * 16 + m] : 0.f;
#pragma unroll
    for (int i = 0; i < 4; ++i)
#pragma unroll
        for (int j = 0; j < 4; ++j)
#pragma unroll
            for (int r = 0; r < 4; ++r) {
                int row = m0 + i * 16 + quad * 4 + r;
                int col = n0 + j * 16 + m;
                stf(&C[(size_t)row * ldc + col], acc[i][j][r] + bv[j]);
            }
}

// ---------------------------------------------------------------------------
// MFMA GEMM (small-N variant, 64x64 block): kept for the Wx GEMM (N=64).
// ---------------------------------------------------------------------------
template <typename TC>
__global__ void mfma_gemm_k(const bf16* __restrict__ A, int lda,
                            const bf16* __restrict__ Bt, int ldb,
                            const float* __restrict__ bias,
                            TC* __restrict__ C, int ldc, int Kd)
{
    const int lane = threadIdx.x & 63;
    const int w = threadIdx.x >> 6;
    const int m = lane & 15, quad = lane >> 4;
    const int m0 = blockIdx.y * 64 + (w >> 1) * 32;
    const int n0 = blockIdx.x * 64 + (w & 1) * 32;
    f32x4 acc[2][2] = {};
    const bf16* a0p = A + (size_t)(m0 + m) * lda + quad * 8;
    const bf16* a1p = a0p + (size_t)16 * lda;
    const bf16* b0p = Bt + (size_t)(n0 + m) * ldb + quad * 8;
    const bf16* b1p = b0p + (size_t)16 * ldb;
    for (int k = 0; k < Kd; k += 32) {
        short8 a0 = *(const short8*)(a0p + k);
        short8 a1 = *(const short8*)(a1p + k);
        short8 b0 = *(const short8*)(b0p + k);
        short8 b1 = *(const short8*)(b1p + k);
        acc[0][0] = __builtin_amdgcn_mfma_f32_16x16x32_bf16(a0, b0, acc[0][0], 0, 0, 0);
        acc[0][1] = __builtin_amdgcn_mfma_f32_16x16x32_bf16(a0, b1, acc[0][1], 0, 0, 0);
        acc[1][0] = __builtin_amdgcn_mfma_f32_16x16x32_bf16(a1, b0, acc[1][0], 0, 0, 0);
        acc[1][1] = __builtin_amdgcn_mfma_f32_16x16x32_bf16(a1, b1, acc[1][1], 0, 0, 0);
    }
#pragma unroll
    for (int i = 0; i < 2; ++i)
#pragma unroll
        for (int j = 0; j < 2; ++j)
#pragma unroll
            for (int r = 0; r < 4; ++r) {
                int row = m0 + i * 16 + quad * 4 + r;
                int col = n0 + j * 16 + (lane & 15);
                float vv = acc[i][j][r] + (bias ? bias[col] : 0.f);
                stf(&C[(size_t)row * ldc + col], vv);
            }
}

// ---------------------------------------------------------------------------
// FUSED attention v4: scores + online softmax + (attn@V).
// v4 = v3 with the t/m role swap in the srow mapping: srow = w*256 + m*16 + t
// so lane m's acc[t] registers hold 16 CONSECUTIVE attn columns m*16..m*16+15.
// The 128 MB attn output is then written as f32x4 NT stores (16 B/lane)
// instead of scalar dword stores. R9 profile showed the kernel runs exactly
// at hbm_bytes / 2 TB/s = the scalar-store ceiling; dwordx4 should lift the
// write throughput to ~5-6 TB/s. K-load coalescing is unchanged (16x 64 B row
// segments per instruction under either mapping); softmax reduction sets and
// P staging semantics are identical.
// ---------------------------------------------------------------------------
__global__ void attn_fused_k(const bf16* __restrict__ q, const bf16* __restrict__ k,
                             const bf16* __restrict__ vT,
                             float* __restrict__ attn, bf16* __restrict__ o)
{
    const int n = blockIdx.x;
    const int bh = ((n >> 9) << 3) | (n & 7);
    const int rt = (n >> 3) & 63;
    const int b = bh >> 3, h = bh & 7;
    const int w = threadIdx.x >> 6;
    const int lane = threadIdx.x & 63;
    const int m = lane & 15, quad = lane >> 4;
    __shared__ float pm[4][16], ps[4][16];
    __shared__ bf16 P[16][524];   // half-tile: 16 rows x 512 cols, stride 524

    // ---- scores: each wave owns 256 cols; lane m owns cols m*16..m*16+15 ----
    const bf16* qp = q + (size_t)(b * LL + rt * 16 + m) * DD + h * EE + quad * 8;
    short8 a0 = *(const short8*)(qp);
    short8 a1 = *(const short8*)(qp + 32);

    f32x4 acc[16];
#pragma unroll
    for (int t = 0; t < 16; ++t) {
        int srow = w * 256 + m * 16 + t;
        const bf16* kp = k + (size_t)(b * LL + srow) * DD + h * EE + quad * 8;
        short8 b0 = *(const short8*)(kp);
        short8 b1 = *(const short8*)(kp + 32);
        f32x4 c = {};
        c = __builtin_amdgcn_mfma_f32_16x16x32_bf16(a0, b0, c, 0, 0, 0);
        c = __builtin_amdgcn_mfma_f32_16x16x32_bf16(a1, b1, c, 0, 0, 0);
        acc[t] = c;
    }

    // ---- softmax pass 1: wave-local max, exp in-place, wave-local sum ----
#pragma unroll
    for (int r = 0; r < 4; ++r) {
        float mx = -1e30f;
#pragma unroll
        for (int t = 0; t < 16; ++t) { acc[t][r] *= 0.125f; mx = fmaxf(mx, acc[t][r]); }
        mx = fmaxf(mx, __shfl_xor(mx, 1)); mx = fmaxf(mx, __shfl_xor(mx, 2));
        mx = fmaxf(mx, __shfl_xor(mx, 4)); mx = fmaxf(mx, __shfl_xor(mx, 8));
        float s = 0.f;
#pragma unroll
        for (int t = 0; t < 16; ++t) { float e = __expf(acc[t][r] - mx); acc[t][r] = e; s += e; }
        s += __shfl_xor(s, 1); s += __shfl_xor(s, 2);
        s += __shfl_xor(s, 4); s += __shfl_xor(s, 8);
        if (m == 0) { pm[w][quad * 4 + r] = mx; ps[w][quad * 4 + r] = s; }
    }
    __syncthreads();

    // ---- softmax pass 2: combine; f32x4 NT-store attn; stage P half-0 ----
    float sc[4];
#pragma unroll
    for (int r = 0; r < 4; ++r) {
        const int row = quad * 4 + r;
        float m0 = pm[0][row], m1 = pm[1][row], m2 = pm[2][row], m3 = pm[3][row];
        float M = fmaxf(fmaxf(m0, m1), fmaxf(m2, m3));
        float e0 = __expf(m0 - M), e1 = __expf(m1 - M), e2 = __expf(m2 - M), e3 = __expf(m3 - M);
        float T = ps[0][row] * e0 + ps[1][row] * e1 + ps[2][row] * e2 + ps[3][row] * e3;
        float ew = (w == 0) ? e0 : (w == 1) ? e1 : (w == 2) ? e2 : e3;
        sc[r] = ew / T;
    }
#pragma unroll
    for (int r = 0; r < 4; ++r) {
        const int row = quad * 4 + r;
        float* op = attn + ((size_t)bh * LL + rt * 16 + row) * LL + w * 256 + m * 16;
#pragma unroll
        for (int g = 0; g < 4; ++g) {
            f32x4 pv;
            pv[0] = acc[4 * g + 0][r] * sc[r];
            pv[1] = acc[4 * g + 1][r] * sc[r];
            pv[2] = acc[4 * g + 2][r] * sc[r];
            pv[3] = acc[4 * g + 3][r] * sc[r];
            __builtin_nontemporal_store(pv, (f32x4*)op + g);
            if (w < 2) {
                P[row][(w & 1) * 256 + m * 16 + 4 * g + 0] = __float2bfloat16(pv[0]);
                P[row][(w & 1) * 256 + m * 16 + 4 * g + 1] = __float2bfloat16(pv[1]);
                P[row][(w & 1) * 256 + m * 16 + 4 * g + 2] = __float2bfloat16(pv[2]);
                P[row][(w & 1) * 256 + m * 16 + 4 * g + 3] = __float2bfloat16(pv[3]);
            }
        }
    }
    __syncthreads();   // P half-0 ready

    // ---- phase B: O = P @ V^T, two K-halves through the half-tile ----
    const bf16* vp = vT + (size_t)(bh * EE + w * 16 + m) * LL + quad * 8;
    f32x4 oacc = {};
    for (int k0 = 0; k0 < 512; k0 += 32) {
        short8 af = *(const short8*)(&P[m][k0 + quad * 8]);
        short8 bf = *(const short8*)(vp + k0);
        oacc = __builtin_amdgcn_mfma_f32_16x16x32_bf16(af, bf, oacc, 0, 0, 0);
    }
    __syncthreads();   // everyone done reading half-0
    if (w >= 2) {
#pragma unroll
        for (int r = 0; r < 4; ++r) {
            const int row = quad * 4 + r;
#pragma unroll
            for (int t = 0; t < 16; ++t)
                P[row][(w & 1) * 256 + m * 16 + t] = __float2bfloat16(acc[t][r] * sc[r]);
        }
    }
    __syncthreads();   // P half-1 ready
    for (int k0 = 512; k0 < 1024; k0 += 32) {
        short8 af = *(const short8*)(&P[m][k0 - 512 + quad * 8]);
        short8 bf = *(const short8*)(vp + k0);
        oacc = __builtin_amdgcn_mfma_f32_16x16x32_bf16(af, bf, oacc, 0, 0, 0);
    }
#pragma unroll
    for (int r = 0; r < 4; ++r) {
        int row = rt * 16 + quad * 4 + r;
        stf(&o[(size_t)(b * LL + row) * DD + h * EE + w * 16 + m], oacc[r]);
    }
}

// ---------------------------------------------------------------------------
// VALU tiled GEMM (kept for the tiny Wdt GEMM with f32 A).
// SP=true fuses softplus into the epilogue (used for dt).
// ---------------------------------------------------------------------------
template <typename TA, typename TC, bool SP>
__global__ void gemm_k(const TA* __restrict__ A, int lda,
                       const float* __restrict__ B, int ldb,
                       const float* __restrict__ bias,
                       TC* __restrict__ C, int ldc,
                       int M, int N, int Kd)
{
    __shared__ float As[32][33];
    __shared__ float Bs[32][33];
    const int tid = threadIdx.x;
    const int tx = tid & 31;
    const int ty = tid >> 5;
    const int rowBase = blockIdx.y * 32;
    const int colBase = blockIdx.x * 32;
    float acc[4] = {0.f, 0.f, 0.f, 0.f};

    for (int k0 = 0; k0 < Kd; k0 += 32) {
#pragma unroll
        for (int i = 0; i < 4; ++i) {
            int r = ty + 8 * i;
            As[r][tx] = ldf(&A[(size_t)(rowBase + r) * lda + k0 + tx]);
            Bs[r][tx] = B[(size_t)(k0 + r) * ldb + colBase + tx];
        }
        __syncthreads();
#pragma unroll 8
        for (int kk = 0; kk < 32; ++kk) {
            float bv = Bs[kk][tx];
#pragma unroll
            for (int i = 0; i < 4; ++i) acc[i] += As[ty + 8 * i][kk] * bv;
        }
        __syncthreads();
    }
#pragma unroll
    for (int i = 0; i < 4; ++i) {
        int row = rowBase + ty + 8 * i;
        int col = colBase + tx;
        float r = acc[i] + (bias ? bias[col] : 0.f);
        if (SP) r = (r > 20.f) ? r : log1pf(__expf(r));
        stf(&C[(size_t)row * ldc + col], r);
    }
}

// ---------------------------------------------------------------------------
// out = LayerNorm(a + r) * g + beta.  One block (256 thr) per row of 512.
// ---------------------------------------------------------------------------
template <typename TA, typename TR, typename TO>
__global__ void add_ln_k(const TA* __restrict__ a, const TR* __restrict__ r,
                         const float* __restrict__ g, const float* __restrict__ be,
                         TO* __restrict__ out)
{
    const int row = blockIdx.x;
    const int tid = threadIdx.x;
    __shared__ float red[256];
    const size_t base = (size_t)row * DD;
    float v0 = ldf(&a[base + tid]) + ldf(&r[base + tid]);
    float v1 = ldf(&a[base + 256 + tid]) + ldf(&r[base + 256 + tid]);
    red[tid] = v0 + v1;
    __syncthreads();
    for (int off = 128; off > 0; off >>= 1) {
        if (tid < off) red[tid] += red[tid + off];
        __syncthreads();
    }
    const float mu = red[0] * (1.f / 512.f);
    __syncthreads();
    float d0 = v0 - mu, d1 = v1 - mu;
    red[tid] = d0 * d0 + d1 * d1;
    __syncthreads();
    for (int off = 128; off > 0; off >>= 1) {
        if (tid < off) red[tid] += red[tid + off];
        __syncthreads();
    }
    const float rs = rsqrtf(red[0] * (1.f / 512.f) + 1e-5f);
    stf(&out[base + tid], d0 * rs * g[tid] + be[tid]);
    stf(&out[base + 256 + tid], d1 * rs * g[tid + 256] + be[tid + 256]);
}

// ---------------------------------------------------------------------------
// Depthwise causal conv (K=4) + bias + SiLU.
// ---------------------------------------------------------------------------
__global__ void conv_silu_k(const bf16* __restrict__ xz,
                            const float* __restrict__ w,
                            const float* __restrict__ cb,
                            bf16* __restrict__ xc)
{
    const int idx = blockIdx.x * 256 + threadIdx.x;
    const int c = idx & (DIN - 1);
    const int t = (idx >> 10) & (LL - 1);
    const int b = idx >> 20;
    float acc = cb[c];
    const bf16* xi = xz + (size_t)b * LL * (2 * DIN) + c;
#pragma unroll
    for (int j = 0; j < KK; ++j) {
        int tt = t - (KK - 1) + j;
        if (tt >= 0) acc += w[c * KK + j] * ldf(&xi[(size_t)tt * (2 * DIN)]);
    }
    stf(&xc[idx], acc / (1.f + __expf(-acc)));
}

// ---------------------------------------------------------------------------
// Chunked selective scan, phase 1 (n-in-register).
// ---------------------------------------------------------------------------
__global__ void scan_p1_k(const bf16* __restrict__ dt, const bf16* __restrict__ xc,
                          const float* __restrict__ dbl, const float* __restrict__ Alog,
                          float* __restrict__ P, float* __restrict__ S)
{
    const int d = (blockIdx.x & 3) * 256 + threadIdx.x;   // DIN/256 = 4
    const int c = blockIdx.x >> 2;
    const int b = blockIdx.y;
    float A[NN];
#pragma unroll
    for (int n = 0; n < NN; ++n) A[n] = -__expf(Alog[d * NN + n]);
    const int t0 = c * LC;
    const bf16* dt_b = dt + ((size_t)b * LL + t0) * DIN + d;
    const bf16* xc_b = xc + ((size_t)b * LL + t0) * DIN + d;
    const float* dbl_b = dbl + ((size_t)b * LL + t0) * 64 + RR;   // uniform per wave
    float h[NN];
#pragma unroll
    for (int n = 0; n < NN; ++n) h[n] = 0.f;
    float sdt = 0.f;
#pragma unroll 4
    for (int t = 0; t < LC; ++t) {
        float dtv = ldf(&dt_b[(size_t)t * DIN]);
        float xcv = ldf(&xc_b[(size_t)t * DIN]);
        float dtx = dtv * xcv;
        sdt += dtv;
#pragma unroll
        for (int n = 0; n < NN; ++n) {
            float dA = __expf(dtv * A[n]);
            h[n] = h[n] * dA + dtx * dbl_b[(size_t)t * 64 + n];
        }
    }
    float* Pp = P + (size_t)c * BDN + ((size_t)(b * DIN + d)) * NN;
    float* Sp = S + (size_t)c * BDN + ((size_t)(b * DIN + d)) * NN;
#pragma unroll
    for (int n = 0; n < NN; ++n) { Pp[n] = __expf(sdt * A[n]); Sp[n] = h[n]; }
}

// ---------------------------------------------------------------------------
// Phase 2: serial carry scan over the CC chunks. One thread per bdn.
// ---------------------------------------------------------------------------
__global__ void scan_p2_k(const float* __restrict__ P, const float* __restrict__ S,
                          float* __restrict__ Hc)
{
    const size_t bdn = (size_t)blockIdx.x * 256 + threadIdx.x;
    float h = 0.f;
#pragma unroll
    for (int c = 0; c < CC; ++c) {
        Hc[(size_t)c * BDN + bdn] = h;
        h = S[(size_t)c * BDN + bdn] + P[(size_t)c * BDN + bdn] * h;
    }
}

// ---------------------------------------------------------------------------
// Phase 3 (n-in-register): replay each chunk from its carry-in.
// ---------------------------------------------------------------------------
__global__ void scan_p3_k(const bf16* __restrict__ dt, const bf16* __restrict__ xc,
                          const float* __restrict__ dbl, const float* __restrict__ Alog,
                          const float* __restrict__ Dv, const float* __restrict__ Hc,
                          bf16* __restrict__ xzm)
{
    const int d = (blockIdx.x & 3) * 256 + threadIdx.x;
    const int c = blockIdx.x >> 2;
    const int b = blockIdx.y;
    float A[NN];
#pragma unroll
    for (int n = 0; n < NN; ++n) A[n] = -__expf(Alog[d * NN + n]);
    const float Dp = Dv[d];
    const int t0 = c * LC;
    const bf16* dt_b = dt + ((size_t)b * LL + t0) * DIN + d;
    const bf16* xc_b = xc + ((size_t)b * LL + t0) * DIN + d;
    const float* dbl_b = dbl + ((size_t)b * LL + t0) * 64 + RR;   // uniform per wave
    bf16* xz_b = xzm + ((size_t)b * LL + t0) * (2 * DIN);
    const float* hp = Hc + (size_t)c * BDN + ((size_t)(b * DIN + d)) * NN;
    float h[NN];
#pragma unroll
    for (int n = 0; n < NN; ++n) h[n] = hp[n];
#pragma unroll 2
    for (int t = 0; t < LC; ++t) {
        float dtv = ldf(&dt_b[(size_t)t * DIN]);
        float xcv = ldf(&xc_b[(size_t)t * DIN]);
        float dtx = dtv * xcv;
        float y = 0.f;
#pragma unroll
        for (int n = 0; n < NN; ++n) {
            float dA = __expf(dtv * A[n]);
            h[n] = h[n] * dA + dtx * dbl_b[(size_t)t * 64 + n];
            y += h[n] * dbl_b[(size_t)t * 64 + NN + n];
        }
        float zv = ldf(&xz_b[(size_t)t * (2 * DIN) + DIN + d]);
        float yv = y + xcv * Dp;
        yv *= zv / (1.f + __expf(-zv));
        stf(&xz_b[(size_t)t * (2 * DIN) + d], yv);
    }
}

// ---------------------------------------------------------------------------
extern "C" void kernel_launch(void* const* d_in, const int* in_sizes, int n_in,
                              void* d_out, int out_size, void* d_ws, size_t ws_size,
                              hipStream_t stream)
{
    const float* x    = (const float*)d_in[0];
    const float* Wq   = (const float*)d_in[1];
    const float* bq   = (const float*)d_in[2];
    const float* Wk   = (const float*)d_in[3];
    const float* bk   = (const float*)d_in[4];
    const float* Wv   = (const float*)d_in[5];
    const float* bv   = (const float*)d_in[6];
    const float* Wo   = (const float*)d_in[7];
    const float* bo   = (const float*)d_in[8];
    const float* g1   = (const float*)d_in[9];
    const float* b1   = (const float*)d_in[10];
    const float* g2   = (const float*)d_in[11];
    const float* b2   = (const float*)d_in[12];
    const float* Win  = (const float*)d_in[13];
    const float* cw   = (const float*)d_in[14];
    const float* cb   = (const float*)d_in[15];
    const float* Wx   = (const float*)d_in[16];
    const float* Wdt  = (const float*)d_in[17];
    const float* bdt  = (const float*)d_in[18];
    const float* Alog = (const float*)d_in[19];
    const float* Dv   = (const float*)d_in[20];
    const float* Wout = (const float*)d_in[21];

    float* out  = (float*)d_out;                     // (B,L,D) f32
    float* attn = out + (size_t)BL * DD;             // (B,H,L,L) f32

    const size_t M1 = 1048576;
    bf16* wsb = (bf16*)d_ws;
    bf16* xb   = wsb;                 // 2M bf16 [0,4MB)   (dead after QKV gemms)
    bf16* q    = wsb + 2*M1;          // 2M [4,8MB)  (newx; dead after LN1)
    bf16* kb   = wsb + 4*M1;          // 2M [8,12MB) (dead after attn)
    bf16* v    = wsb + 6*M1;          // 2M [12,16MB) (dead after tpv; reused as ym late)
    bf16* o    = wsb + 8*M1;          // 2M (dead after Wo gemm)
    bf16* x1   = wsb + 10*M1;         // 2M (LIVE through final LN)
    bf16* xz   = wsb + 12*M1;         // 8M
    bf16* xc   = wsb + 20*M1;         // 4M
    bf16* dtb  = wsb + 24*M1;         // 4M
    float* dbl = (float*)(wsb + 28*M1);          // 262144 f32
    bf16* vT   = wsb + 28*M1 + 524288;           // 2M [~59.8MB, +4MB)
    bf16* Wqt  = vT + 2*M1;
    bf16* Wkt  = Wqt + 262144;
    bf16* Wvt  = Wkt + 262144;
    bf16* Wot  = Wvt + 262144;
    bf16* Wint = Wot + 262144;        // 2048x512 = 1M
    bf16* Wxt  = Wint + M1;           // 64x1024
    bf16* Woutt= Wxt + 65536;         // 512x1024   (end ~69.3 MB)
    bf16* newx = q;
    bf16* ym   = v;
    // Scan scratch (CC=32 -> 8MB each), aliased onto regions dead at scan time:
    float* Pp = (float*)xb;    // spans xb+q   [0, 8MB)
    float* Sp = (float*)kb;    // spans kb+v   [8MB, 16MB)  (ym=v written after p2 done)
    float* Hc = (float*)vT;    // spans vT..Wint (8MB exactly; Wxt/Woutt untouched)

    const dim3 blk(256);

    // Stage 0: batched weight transposes + x->bf16 convert, single launch
    TpwJobs tj;
    int t0 = 0, nj = 0;
    auto addjob = [&](const float* in, bf16* outp, int Kd, int Nd) {
        tj.j[nj] = {in, outp, Kd, Nd, Nd / 32, t0};
        t0 += (Nd / 32) * (Kd / 32);
        ++nj;
    };
    addjob(Wq,   Wqt,   DD,  DD);
    addjob(Wk,   Wkt,   DD,  DD);
    addjob(Wv,   Wvt,   DD,  DD);
    addjob(Wo,   Wot,   DD,  DD);
    addjob(Win,  Wint,  DD,  2*DIN);
    addjob(Wx,   Wxt,   DIN, 64);
    addjob(Wout, Woutt, DIN, DD);
    tpw_batch_k<<<dim3(t0 + BL*DD/256), blk, 0, stream>>>(tj, t0, x, xb, BL*DD);

    // QKV projections fused into one launch (Wqt/Wkt/Wvt and q/kb/v contiguous)
    mfma_gemm128_k<bf16><<<dim3(DD/128, BL/128, 3), blk, 0, stream>>>(
        xb, DD, Wqt, (size_t)DD*DD, DD, bq, bk, bv, q, (size_t)2*M1, DD, DD);
    tpv_k<<<dim3(LL/32, EE/32, BB*HH), blk, 0, stream>>>(v, vT);

    // Fused attention: scores + softmax + AV (f32x4 nt-stores attn + bf16 o)
    attn_fused_k<<<dim3((LL/16)*BB*HH), blk, 0, stream>>>(q, kb, vT, attn, o);

    // Output projection + LN1
    mfma_gemm128_k<bf16><<<dim3(DD/128, BL/128, 1), blk, 0, stream>>>(
        o, DD, Wot, 0, DD, bo, nullptr, nullptr, newx, 0, DD, DD);
    add_ln_k<float, bf16, bf16><<<dim3(BL), blk, 0, stream>>>(x, newx, g1, b1, x1);

    // Mamba in-projection
    mfma_gemm128_k<bf16><<<dim3(2*DIN/128, BL/128, 1), blk, 0, stream>>>(
        x1, DD, Wint, 0, DD, nullptr, nullptr, nullptr, xz, 0, 2*DIN, DD);

    // Depthwise conv + SiLU
    conv_silu_k<<<dim3(BL*DIN/256), blk, 0, stream>>>(xz, cw, cb, xc);

    // dbl = xc @ Wx (f32 out, N=64 -> small-tile GEMM)
    mfma_gemm_k<float><<<dim3(64/64, BL/64), blk, 0, stream>>>(xc, DIN, Wxt, DIN, nullptr, dbl, 64, DIN);

    // dt = softplus(dbl[:, :32] @ Wdt + bdt)  (softplus fused in epilogue)
    gemm_k<float, bf16, true><<<dim3(DIN/32, BL/32), blk, 0, stream>>>(dbl, 64, Wdt, DIN, bdt, dtb, DIN, BL, DIN, RR);

    // Chunked selective scan (3 phases) + skip + gate (y -> xi half of xz)
    scan_p1_k<<<dim3((DIN/256)*CC, BB), blk, 0, stream>>>(dtb, xc, dbl, Alog, Pp, Sp);
    scan_p2_k<<<dim3(BDN/256), blk, 0, stream>>>(Pp, Sp, Hc);
    scan_p3_k<<<dim3((DIN/256)*CC, BB), blk, 0, stream>>>(dtb, xc, dbl, Alog, Dv, Hc, xz);

    // Mamba out-projection
    mfma_gemm128_k<bf16><<<dim3(DD/128, BL/128, 1), blk, 0, stream>>>(
        xz, 2*DIN, Woutt, 0, DIN, nullptr, nullptr, nullptr, ym, 0, DD, DIN);

    // Final residual LN -> f32 out
    add_ln_k<bf16, bf16, float><<<dim3(BL), blk, 0, stream>>>(x1, ym, g2, b2, out);
}

// Round 15
// 518.973 us; speedup vs baseline: 1.3122x; 1.3122x over previous
//
#include <hip/hip_runtime.h>
#include <hip/hip_bf16.h>

// Problem constants (B=4, L=1024, D=512, H=8, E=64, DIN=1024, N=16, K=4, R=32)
#define BB 4
#define LL 1024
#define DD 512
#define HH 8
#define EE 64
#define DIN 1024
#define NN 16
#define KK 4
#define RR 32
#define BL (BB*LL)   // 4096 rows
#define CC 32        // scan chunks (32 -> LC=32, 2048 waves in p1/p3)
#define LC (LL/CC)   // 32 steps per chunk
#define BDN (BB*DIN*NN)   // 65536 independent recurrences

using bf16 = __hip_bfloat16;
typedef __attribute__((ext_vector_type(8))) short short8;   // 8 bf16 = 4 VGPRs
typedef __attribute__((ext_vector_type(4))) float f32x4;

__device__ __forceinline__ float ldf(const float* p) { return *p; }
__device__ __forceinline__ float ldf(const bf16* p) { return __bfloat162float(*p); }
__device__ __forceinline__ void stf(float* p, float v) { *p = v; }
__device__ __forceinline__ void stf(bf16* p, float v) { *p = __float2bfloat16(v); }

// ---------------------------------------------------------------------------
// Batched weight transpose + f32->bf16 convert tail, one launch.
// ---------------------------------------------------------------------------
struct TpwJob { const float* in; bf16* out; int Kd, Nd, gx, tile0; };
struct TpwJobs { TpwJob j[7]; };

__global__ void tpw_batch_k(TpwJobs jobs, int tile_total,
                            const float* __restrict__ cvt_in,
                            bf16* __restrict__ cvt_out, int cvt_n)
{
    const int tile = blockIdx.x;
    if (tile >= tile_total) {
        int i = (tile - tile_total) * 256 + threadIdx.x;
        if (i < cvt_n) cvt_out[i] = __float2bfloat16(cvt_in[i]);
        return;
    }
    int ji = 0;
#pragma unroll
    for (int i = 1; i < 7; ++i) if (tile >= jobs.j[i].tile0) ji = i;
    const TpwJob jb = jobs.j[ji];
    const int lt = tile - jb.tile0;
    const int n0 = (lt % jb.gx) * 32;
    const int k0 = (lt / jb.gx) * 32;

    __shared__ float t[32][33];
    const int tx = threadIdx.x & 31, ty = threadIdx.x >> 5;
#pragma unroll
    for (int i = 0; i < 4; ++i)
        t[ty + 8 * i][tx] = jb.in[(size_t)(k0 + ty + 8 * i) * jb.Nd + n0 + tx];
    __syncthreads();
#pragma unroll
    for (int i = 0; i < 4; ++i)
        jb.out[(size_t)(n0 + ty + 8 * i) * jb.Kd + k0 + tx] = __float2bfloat16(t[tx][ty + 8 * i]);
}

// ---------------------------------------------------------------------------
// V transpose per head: vT[bh][e][l] = v[b][l][h*64+e]
// ---------------------------------------------------------------------------
__global__ void tpv_k(const bf16* __restrict__ v, bf16* __restrict__ vT)
{
    __shared__ float t[32][33];
    const int l0 = blockIdx.x * 32;
    const int e0 = blockIdx.y * 32;
    const int bh = blockIdx.z, b = bh >> 3, h = bh & 7;
    const int tx = threadIdx.x & 31, ty = threadIdx.x >> 5;
#pragma unroll
    for (int i = 0; i < 4; ++i)
        t[ty + 8 * i][tx] = ldf(&v[(size_t)(b * LL + l0 + ty + 8 * i) * DD + h * EE + e0 + tx]);
    __syncthreads();
#pragma unroll
    for (int i = 0; i < 4; ++i)
        stf(&vT[(size_t)(bh * EE + e0 + ty + 8 * i) * LL + l0 + tx], t[tx][ty + 8 * i]);
}

// ---------------------------------------------------------------------------
// Big MFMA GEMM: 128x128 block tile, 4 waves 2x2, 64x64 per wave (acc[4][4]).
// Optional z-batching. Grid (N/128, M/128, nz).
// ---------------------------------------------------------------------------
template <typename TC>
__global__ void mfma_gemm128_k(const bf16* __restrict__ A, int lda,
                               const bf16* __restrict__ Bt0, size_t bstride, int ldb,
                               const float* __restrict__ bias0,
                               const float* __restrict__ bias1,
                               const float* __restrict__ bias2,
                               TC* __restrict__ C0, size_t cstride, int ldc, int Kd)
{
    const int z = blockIdx.z;
    const bf16* Bt = Bt0 + (size_t)z * bstride;
    TC* C = C0 + (size_t)z * cstride;
    const float* bias = (z == 0) ? bias0 : (z == 1) ? bias1 : bias2;

    const int lane = threadIdx.x & 63;
    const int w = threadIdx.x >> 6;
    const int m = lane & 15, quad = lane >> 4;
    const int m0 = blockIdx.y * 128 + (w >> 1) * 64;
    const int n0 = blockIdx.x * 128 + (w & 1) * 64;

    f32x4 acc[4][4] = {};
    const bf16* ap = A + (size_t)(m0 + m) * lda + quad * 8;
    const bf16* bp = Bt + (size_t)(n0 + m) * ldb + quad * 8;
    const size_t rsa = (size_t)16 * lda;
    const size_t rsb = (size_t)16 * ldb;
    for (int k = 0; k < Kd; k += 32) {
        short8 a[4], b[4];
#pragma unroll
        for (int i = 0; i < 4; ++i) a[i] = *(const short8*)(ap + i * rsa + k);
#pragma unroll
        for (int j = 0; j < 4; ++j) b[j] = *(const short8*)(bp + j * rsb + k);
#pragma unroll
        for (int i = 0; i < 4; ++i)
#pragma unroll
            for (int j = 0; j < 4; ++j)
                acc[i][j] = __builtin_amdgcn_mfma_f32_16x16x32_bf16(a[i], b[j], acc[i][j], 0, 0, 0);
    }
    float bv[4];
#pragma unroll
    for (int j = 0; j < 4; ++j) bv[j] = bias ? bias[n0 + j * 16 + m] : 0.f;
#pragma unroll
    for (int i = 0; i < 4; ++i)
#pragma unroll
        for (int j = 0; j < 4; ++j)
#pragma unroll
            for (int r = 0; r < 4; ++r) {
                int row = m0 + i * 16 + quad * 4 + r;
                int col = n0 + j * 16 + m;
                stf(&C[(size_t)row * ldc + col], acc[i][j][r] + bv[j]);
            }
}

// ---------------------------------------------------------------------------
// MFMA GEMM (small-N variant, 64x64 block): kept for the Wx GEMM (N=64).
// ---------------------------------------------------------------------------
template <typename TC>
__global__ void mfma_gemm_k(const bf16* __restrict__ A, int lda,
                            const bf16* __restrict__ Bt, int ldb,
                            const float* __restrict__ bias,
                            TC* __restrict__ C, int ldc, int Kd)
{
    const int lane = threadIdx.x & 63;
    const int w = threadIdx.x >> 6;
    const int m = lane & 15, quad = lane >> 4;
    const int m0 = blockIdx.y * 64 + (w >> 1) * 32;
    const int n0 = blockIdx.x * 64 + (w & 1) * 32;
    f32x4 acc[2][2] = {};
    const bf16* a0p = A + (size_t)(m0 + m) * lda + quad * 8;
    const bf16* a1p = a0p + (size_t)16 * lda;
    const bf16* b0p = Bt + (size_t)(n0 + m) * ldb + quad * 8;
    const bf16* b1p = b0p + (size_t)16 * ldb;
    for (int k = 0; k < Kd; k += 32) {
        short8 a0 = *(const short8*)(a0p + k);
        short8 a1 = *(const short8*)(a1p + k);
        short8 b0 = *(const short8*)(b0p + k);
        short8 b1 = *(const short8*)(b1p + k);
        acc[0][0] = __builtin_amdgcn_mfma_f32_16x16x32_bf16(a0, b0, acc[0][0], 0, 0, 0);
        acc[0][1] = __builtin_amdgcn_mfma_f32_16x16x32_bf16(a0, b1, acc[0][1], 0, 0, 0);
        acc[1][0] = __builtin_amdgcn_mfma_f32_16x16x32_bf16(a1, b0, acc[1][0], 0, 0, 0);
        acc[1][1] = __builtin_amdgcn_mfma_f32_16x16x32_bf16(a1, b1, acc[1][1], 0, 0, 0);
    }
#pragma unroll
    for (int i = 0; i < 2; ++i)
#pragma unroll
        for (int j = 0; j < 2; ++j)
#pragma unroll
            for (int r = 0; r < 4; ++r) {
                int row = m0 + i * 16 + quad * 4 + r;
                int col = n0 + j * 16 + (lane & 15);
                float vv = acc[i][j][r] + (bias ? bias[col] : 0.f);
                stf(&C[(size_t)row * ldc + col], vv);
            }
}

// ---------------------------------------------------------------------------
// FUSED attention v5: scores + online softmax + (attn@V).
// v5 fixes v4's write amplification (WRITE_SIZE 348 MB vs 135 ideal; 16 B NT
// chunks at 64 B stride left 3/4 of each sector uncovered with L2 bypassed).
// New mapping: srow = w*256 + (t>>2)*64 + m*4 + (t&3), so register group
// g = t>>2 holds cols g*64 + m*4 .. +3 -> each f32x4 NT store is CONTIGUOUS
// across lanes (256 B per quad, full sectors, 1024 B per wave instruction).
// K-load coalescing unchanged (16 x 256 B row segments / instr). Softmax
// reduce sets identical. P staging is 8 B/lane contiguous (conflict-free).
// Phase B reads P rows, which are complete under any intra-wave col split.
// ---------------------------------------------------------------------------
__global__ void attn_fused_k(const bf16* __restrict__ q, const bf16* __restrict__ k,
                             const bf16* __restrict__ vT,
                             float* __restrict__ attn, bf16* __restrict__ o)
{
    const int n = blockIdx.x;
    const int bh = ((n >> 9) << 3) | (n & 7);
    const int rt = (n >> 3) & 63;
    const int b = bh >> 3, h = bh & 7;
    const int w = threadIdx.x >> 6;
    const int lane = threadIdx.x & 63;
    const int m = lane & 15, quad = lane >> 4;
    __shared__ float pm[4][16], ps[4][16];
    __shared__ bf16 P[16][524];   // half-tile: 16 rows x 512 cols, stride 524

    // ---- scores: wave w owns cols w*256..w*256+255; lane m's reg group g
    //      holds cols g*64 + m*4 .. +3 ----
    const bf16* qp = q + (size_t)(b * LL + rt * 16 + m) * DD + h * EE + quad * 8;
    short8 a0 = *(const short8*)(qp);
    short8 a1 = *(const short8*)(qp + 32);

    f32x4 acc[16];
#pragma unroll
    for (int t = 0; t < 16; ++t) {
        int srow = w * 256 + (t >> 2) * 64 + m * 4 + (t & 3);
        const bf16* kp = k + (size_t)(b * LL + srow) * DD + h * EE + quad * 8;
        short8 b0 = *(const short8*)(kp);
        short8 b1 = *(const short8*)(kp + 32);
        f32x4 c = {};
        c = __builtin_amdgcn_mfma_f32_16x16x32_bf16(a0, b0, c, 0, 0, 0);
        c = __builtin_amdgcn_mfma_f32_16x16x32_bf16(a1, b1, c, 0, 0, 0);
        acc[t] = c;
    }

    // ---- softmax pass 1: wave-local max, exp in-place, wave-local sum ----
#pragma unroll
    for (int r = 0; r < 4; ++r) {
        float mx = -1e30f;
#pragma unroll
        for (int t = 0; t < 16; ++t) { acc[t][r] *= 0.125f; mx = fmaxf(mx, acc[t][r]); }
        mx = fmaxf(mx, __shfl_xor(mx, 1)); mx = fmaxf(mx, __shfl_xor(mx, 2));
        mx = fmaxf(mx, __shfl_xor(mx, 4)); mx = fmaxf(mx, __shfl_xor(mx, 8));
        float s = 0.f;
#pragma unroll
        for (int t = 0; t < 16; ++t) { float e = __expf(acc[t][r] - mx); acc[t][r] = e; s += e; }
        s += __shfl_xor(s, 1); s += __shfl_xor(s, 2);
        s += __shfl_xor(s, 4); s += __shfl_xor(s, 8);
        if (m == 0) { pm[w][quad * 4 + r] = mx; ps[w][quad * 4 + r] = s; }
    }
    __syncthreads();

    // ---- softmax pass 2: combine; contiguous f32x4 NT-store; stage half-0 ----
    float sc[4];
#pragma unroll
    for (int r = 0; r < 4; ++r) {
        const int row = quad * 4 + r;
        float m0 = pm[0][row], m1 = pm[1][row], m2 = pm[2][row], m3 = pm[3][row];
        float M = fmaxf(fmaxf(m0, m1), fmaxf(m2, m3));
        float e0 = __expf(m0 - M), e1 = __expf(m1 - M), e2 = __expf(m2 - M), e3 = __expf(m3 - M);
        float T = ps[0][row] * e0 + ps[1][row] * e1 + ps[2][row] * e2 + ps[3][row] * e3;
        float ew = (w == 0) ? e0 : (w == 1) ? e1 : (w == 2) ? e2 : e3;
        sc[r] = ew / T;
    }
#pragma unroll
    for (int r = 0; r < 4; ++r) {
        const int row = quad * 4 + r;
        float* op = attn + ((size_t)bh * LL + rt * 16 + row) * LL + w * 256;
#pragma unroll
        for (int g = 0; g < 4; ++g) {
            f32x4 pv;
            pv[0] = acc[4 * g + 0][r] * sc[r];
            pv[1] = acc[4 * g + 1][r] * sc[r];
            pv[2] = acc[4 * g + 2][r] * sc[r];
            pv[3] = acc[4 * g + 3][r] * sc[r];
            // cols g*64 + m*4 .. +3 -> lanes contiguous within 256 B
            __builtin_nontemporal_store(pv, (f32x4*)(op + g * 64) + m);
            if (w < 2) {
                bf16* pp = &P[row][(w & 1) * 256 + g * 64 + m * 4];
                pp[0] = __float2bfloat16(pv[0]);
                pp[1] = __float2bfloat16(pv[1]);
                pp[2] = __float2bfloat16(pv[2]);
                pp[3] = __float2bfloat16(pv[3]);
            }
        }
    }
    __syncthreads();   // P half-0 ready

    // ---- phase B: O = P @ V^T, two K-halves through the half-tile ----
    const bf16* vp = vT + (size_t)(bh * EE + w * 16 + m) * LL + quad * 8;
    f32x4 oacc = {};
    for (int k0 = 0; k0 < 512; k0 += 32) {
        short8 af = *(const short8*)(&P[m][k0 + quad * 8]);
        short8 bf = *(const short8*)(vp + k0);
        oacc = __builtin_amdgcn_mfma_f32_16x16x32_bf16(af, bf, oacc, 0, 0, 0);
    }
    __syncthreads();   // everyone done reading half-0
    if (w >= 2) {
#pragma unroll
        for (int r = 0; r < 4; ++r) {
            const int row = quad * 4 + r;
#pragma unroll
            for (int g = 0; g < 4; ++g) {
                bf16* pp = &P[row][(w & 1) * 256 + g * 64 + m * 4];
                pp[0] = __float2bfloat16(acc[4 * g + 0][r] * sc[r]);
                pp[1] = __float2bfloat16(acc[4 * g + 1][r] * sc[r]);
                pp[2] = __float2bfloat16(acc[4 * g + 2][r] * sc[r]);
                pp[3] = __float2bfloat16(acc[4 * g + 3][r] * sc[r]);
            }
        }
    }
    __syncthreads();   // P half-1 ready
    for (int k0 = 512; k0 < 1024; k0 += 32) {
        short8 af = *(const short8*)(&P[m][k0 - 512 + quad * 8]);
        short8 bf = *(const short8*)(vp + k0);
        oacc = __builtin_amdgcn_mfma_f32_16x16x32_bf16(af, bf, oacc, 0, 0, 0);
    }
#pragma unroll
    for (int r = 0; r < 4; ++r) {
        int row = rt * 16 + quad * 4 + r;
        stf(&o[(size_t)(b * LL + row) * DD + h * EE + w * 16 + m], oacc[r]);
    }
}

// ---------------------------------------------------------------------------
// VALU tiled GEMM (kept for the tiny Wdt GEMM with f32 A).
// SP=true fuses softplus into the epilogue (used for dt).
// ---------------------------------------------------------------------------
template <typename TA, typename TC, bool SP>
__global__ void gemm_k(const TA* __restrict__ A, int lda,
                       const float* __restrict__ B, int ldb,
                       const float* __restrict__ bias,
                       TC* __restrict__ C, int ldc,
                       int M, int N, int Kd)
{
    __shared__ float As[32][33];
    __shared__ float Bs[32][33];
    const int tid = threadIdx.x;
    const int tx = tid & 31;
    const int ty = tid >> 5;
    const int rowBase = blockIdx.y * 32;
    const int colBase = blockIdx.x * 32;
    float acc[4] = {0.f, 0.f, 0.f, 0.f};

    for (int k0 = 0; k0 < Kd; k0 += 32) {
#pragma unroll
        for (int i = 0; i < 4; ++i) {
            int r = ty + 8 * i;
            As[r][tx] = ldf(&A[(size_t)(rowBase + r) * lda + k0 + tx]);
            Bs[r][tx] = B[(size_t)(k0 + r) * ldb + colBase + tx];
        }
        __syncthreads();
#pragma unroll 8
        for (int kk = 0; kk < 32; ++kk) {
            float bv = Bs[kk][tx];
#pragma unroll
            for (int i = 0; i < 4; ++i) acc[i] += As[ty + 8 * i][kk] * bv;
        }
        __syncthreads();
    }
#pragma unroll
    for (int i = 0; i < 4; ++i) {
        int row = rowBase + ty + 8 * i;
        int col = colBase + tx;
        float r = acc[i] + (bias ? bias[col] : 0.f);
        if (SP) r = (r > 20.f) ? r : log1pf(__expf(r));
        stf(&C[(size_t)row * ldc + col], r);
    }
}

// ---------------------------------------------------------------------------
// out = LayerNorm(a + r) * g + beta.  One block (256 thr) per row of 512.
// ---------------------------------------------------------------------------
template <typename TA, typename TR, typename TO>
__global__ void add_ln_k(const TA* __restrict__ a, const TR* __restrict__ r,
                         const float* __restrict__ g, const float* __restrict__ be,
                         TO* __restrict__ out)
{
    const int row = blockIdx.x;
    const int tid = threadIdx.x;
    __shared__ float red[256];
    const size_t base = (size_t)row * DD;
    float v0 = ldf(&a[base + tid]) + ldf(&r[base + tid]);
    float v1 = ldf(&a[base + 256 + tid]) + ldf(&r[base + 256 + tid]);
    red[tid] = v0 + v1;
    __syncthreads();
    for (int off = 128; off > 0; off >>= 1) {
        if (tid < off) red[tid] += red[tid + off];
        __syncthreads();
    }
    const float mu = red[0] * (1.f / 512.f);
    __syncthreads();
    float d0 = v0 - mu, d1 = v1 - mu;
    red[tid] = d0 * d0 + d1 * d1;
    __syncthreads();
    for (int off = 128; off > 0; off >>= 1) {
        if (tid < off) red[tid] += red[tid + off];
        __syncthreads();
    }
    const float rs = rsqrtf(red[0] * (1.f / 512.f) + 1e-5f);
    stf(&out[base + tid], d0 * rs * g[tid] + be[tid]);
    stf(&out[base + 256 + tid], d1 * rs * g[tid + 256] + be[tid + 256]);
}

// ---------------------------------------------------------------------------
// Depthwise causal conv (K=4) + bias + SiLU.
// ---------------------------------------------------------------------------
__global__ void conv_silu_k(const bf16* __restrict__ xz,
                            const float* __restrict__ w,
                            const float* __restrict__ cb,
                            bf16* __restrict__ xc)
{
    const int idx = blockIdx.x * 256 + threadIdx.x;
    const int c = idx & (DIN - 1);
    const int t = (idx >> 10) & (LL - 1);
    const int b = idx >> 20;
    float acc = cb[c];
    const bf16* xi = xz + (size_t)b * LL * (2 * DIN) + c;
#pragma unroll
    for (int j = 0; j < KK; ++j) {
        int tt = t - (KK - 1) + j;
        if (tt >= 0) acc += w[c * KK + j] * ldf(&xi[(size_t)tt * (2 * DIN)]);
    }
    stf(&xc[idx], acc / (1.f + __expf(-acc)));
}

// ---------------------------------------------------------------------------
// Chunked selective scan, phase 1 (n-in-register).
// ---------------------------------------------------------------------------
__global__ void scan_p1_k(const bf16* __restrict__ dt, const bf16* __restrict__ xc,
                          const float* __restrict__ dbl, const float* __restrict__ Alog,
                          float* __restrict__ P, float* __restrict__ S)
{
    const int d = (blockIdx.x & 3) * 256 + threadIdx.x;   // DIN/256 = 4
    const int c = blockIdx.x >> 2;
    const int b = blockIdx.y;
    float A[NN];
#pragma unroll
    for (int n = 0; n < NN; ++n) A[n] = -__expf(Alog[d * NN + n]);
    const int t0 = c * LC;
    const bf16* dt_b = dt + ((size_t)b * LL + t0) * DIN + d;
    const bf16* xc_b = xc + ((size_t)b * LL + t0) * DIN + d;
    const float* dbl_b = dbl + ((size_t)b * LL + t0) * 64 + RR;   // uniform per wave
    float h[NN];
#pragma unroll
    for (int n = 0; n < NN; ++n) h[n] = 0.f;
    float sdt = 0.f;
#pragma unroll 4
    for (int t = 0; t < LC; ++t) {
        float dtv = ldf(&dt_b[(size_t)t * DIN]);
        float xcv = ldf(&xc_b[(size_t)t * DIN]);
        float dtx = dtv * xcv;
        sdt += dtv;
#pragma unroll
        for (int n = 0; n < NN; ++n) {
            float dA = __expf(dtv * A[n]);
            h[n] = h[n] * dA + dtx * dbl_b[(size_t)t * 64 + n];
        }
    }
    float* Pp = P + (size_t)c * BDN + ((size_t)(b * DIN + d)) * NN;
    float* Sp = S + (size_t)c * BDN + ((size_t)(b * DIN + d)) * NN;
#pragma unroll
    for (int n = 0; n < NN; ++n) { Pp[n] = __expf(sdt * A[n]); Sp[n] = h[n]; }
}

// ---------------------------------------------------------------------------
// Phase 2: serial carry scan over the CC chunks. One thread per bdn.
// ---------------------------------------------------------------------------
__global__ void scan_p2_k(const float* __restrict__ P, const float* __restrict__ S,
                          float* __restrict__ Hc)
{
    const size_t bdn = (size_t)blockIdx.x * 256 + threadIdx.x;
    float h = 0.f;
#pragma unroll
    for (int c = 0; c < CC; ++c) {
        Hc[(size_t)c * BDN + bdn] = h;
        h = S[(size_t)c * BDN + bdn] + P[(size_t)c * BDN + bdn] * h;
    }
}

// ---------------------------------------------------------------------------
// Phase 3 (n-in-register): replay each chunk from its carry-in.
// ---------------------------------------------------------------------------
__global__ void scan_p3_k(const bf16* __restrict__ dt, const bf16* __restrict__ xc,
                          const float* __restrict__ dbl, const float* __restrict__ Alog,
                          const float* __restrict__ Dv, const float* __restrict__ Hc,
                          bf16* __restrict__ xzm)
{
    const int d = (blockIdx.x & 3) * 256 + threadIdx.x;
    const int c = blockIdx.x >> 2;
    const int b = blockIdx.y;
    float A[NN];
#pragma unroll
    for (int n = 0; n < NN; ++n) A[n] = -__expf(Alog[d * NN + n]);
    const float Dp = Dv[d];
    const int t0 = c * LC;
    const bf16* dt_b = dt + ((size_t)b * LL + t0) * DIN + d;
    const bf16* xc_b = xc + ((size_t)b * LL + t0) * DIN + d;
    const float* dbl_b = dbl + ((size_t)b * LL + t0) * 64 + RR;   // uniform per wave
    bf16* xz_b = xzm + ((size_t)b * LL + t0) * (2 * DIN);
    const float* hp = Hc + (size_t)c * BDN + ((size_t)(b * DIN + d)) * NN;
    float h[NN];
#pragma unroll
    for (int n = 0; n < NN; ++n) h[n] = hp[n];
#pragma unroll 2
    for (int t = 0; t < LC; ++t) {
        float dtv = ldf(&dt_b[(size_t)t * DIN]);
        float xcv = ldf(&xc_b[(size_t)t * DIN]);
        float dtx = dtv * xcv;
        float y = 0.f;
#pragma unroll
        for (int n = 0; n < NN; ++n) {
            float dA = __expf(dtv * A[n]);
            h[n] = h[n] * dA + dtx * dbl_b[(size_t)t * 64 + n];
            y += h[n] * dbl_b[(size_t)t * 64 + NN + n];
        }
        float zv = ldf(&xz_b[(size_t)t * (2 * DIN) + DIN + d]);
        float yv = y + xcv * Dp;
        yv *= zv / (1.f + __expf(-zv));
        stf(&xz_b[(size_t)t * (2 * DIN) + d], yv);
    }
}

// ---------------------------------------------------------------------------
extern "C" void kernel_launch(void* const* d_in, const int* in_sizes, int n_in,
                              void* d_out, int out_size, void* d_ws, size_t ws_size,
                              hipStream_t stream)
{
    const float* x    = (const float*)d_in[0];
    const float* Wq   = (const float*)d_in[1];
    const float* bq   = (const float*)d_in[2];
    const float* Wk   = (const float*)d_in[3];
    const float* bk   = (const float*)d_in[4];
    const float* Wv   = (const float*)d_in[5];
    const float* bv   = (const float*)d_in[6];
    const float* Wo   = (const float*)d_in[7];
    const float* bo   = (const float*)d_in[8];
    const float* g1   = (const float*)d_in[9];
    const float* b1   = (const float*)d_in[10];
    const float* g2   = (const float*)d_in[11];
    const float* b2   = (const float*)d_in[12];
    const float* Win  = (const float*)d_in[13];
    const float* cw   = (const float*)d_in[14];
    const float* cb   = (const float*)d_in[15];
    const float* Wx   = (const float*)d_in[16];
    const float* Wdt  = (const float*)d_in[17];
    const float* bdt  = (const float*)d_in[18];
    const float* Alog = (const float*)d_in[19];
    const float* Dv   = (const float*)d_in[20];
    const float* Wout = (const float*)d_in[21];

    float* out  = (float*)d_out;                     // (B,L,D) f32
    float* attn = out + (size_t)BL * DD;             // (B,H,L,L) f32

    const size_t M1 = 1048576;
    bf16* wsb = (bf16*)d_ws;
    bf16* xb   = wsb;                 // 2M bf16 [0,4MB)   (dead after QKV gemms)
    bf16* q    = wsb + 2*M1;          // 2M [4,8MB)  (newx; dead after LN1)
    bf16* kb   = wsb + 4*M1;          // 2M [8,12MB) (dead after attn)
    bf16* v    = wsb + 6*M1;          // 2M [12,16MB) (dead after tpv; reused as ym late)
    bf16* o    = wsb + 8*M1;          // 2M (dead after Wo gemm)
    bf16* x1   = wsb + 10*M1;         // 2M (LIVE through final LN)
    bf16* xz   = wsb + 12*M1;         // 8M
    bf16* xc   = wsb + 20*M1;         // 4M
    bf16* dtb  = wsb + 24*M1;         // 4M
    float* dbl = (float*)(wsb + 28*M1);          // 262144 f32
    bf16* vT   = wsb + 28*M1 + 524288;           // 2M [~59.8MB, +4MB)
    bf16* Wqt  = vT + 2*M1;
    bf16* Wkt  = Wqt + 262144;
    bf16* Wvt  = Wkt + 262144;
    bf16* Wot  = Wvt + 262144;
    bf16* Wint = Wot + 262144;        // 2048x512 = 1M
    bf16* Wxt  = Wint + M1;           // 64x1024
    bf16* Woutt= Wxt + 65536;         // 512x1024   (end ~69.3 MB)
    bf16* newx = q;
    bf16* ym   = v;
    // Scan scratch (CC=32 -> 8MB each), aliased onto regions dead at scan time:
    float* Pp = (float*)xb;    // spans xb+q   [0, 8MB)
    float* Sp = (float*)kb;    // spans kb+v   [8MB, 16MB)  (ym=v written after p2 done)
    float* Hc = (float*)vT;    // spans vT..Wint (8MB exactly; Wxt/Woutt untouched)

    const dim3 blk(256);

    // Stage 0: batched weight transposes + x->bf16 convert, single launch
    TpwJobs tj;
    int t0 = 0, nj = 0;
    auto addjob = [&](const float* in, bf16* outp, int Kd, int Nd) {
        tj.j[nj] = {in, outp, Kd, Nd, Nd / 32, t0};
        t0 += (Nd / 32) * (Kd / 32);
        ++nj;
    };
    addjob(Wq,   Wqt,   DD,  DD);
    addjob(Wk,   Wkt,   DD,  DD);
    addjob(Wv,   Wvt,   DD,  DD);
    addjob(Wo,   Wot,   DD,  DD);
    addjob(Win,  Wint,  DD,  2*DIN);
    addjob(Wx,   Wxt,   DIN, 64);
    addjob(Wout, Woutt, DIN, DD);
    tpw_batch_k<<<dim3(t0 + BL*DD/256), blk, 0, stream>>>(tj, t0, x, xb, BL*DD);

    // QKV projections fused into one launch (Wqt/Wkt/Wvt and q/kb/v contiguous)
    mfma_gemm128_k<bf16><<<dim3(DD/128, BL/128, 3), blk, 0, stream>>>(
        xb, DD, Wqt, (size_t)DD*DD, DD, bq, bk, bv, q, (size_t)2*M1, DD, DD);
    tpv_k<<<dim3(LL/32, EE/32, BB*HH), blk, 0, stream>>>(v, vT);

    // Fused attention: scores + softmax + AV (contiguous f32x4 NT attn stores)
    attn_fused_k<<<dim3((LL/16)*BB*HH), blk, 0, stream>>>(q, kb, vT, attn, o);

    // Output projection + LN1
    mfma_gemm128_k<bf16><<<dim3(DD/128, BL/128, 1), blk, 0, stream>>>(
        o, DD, Wot, 0, DD, bo, nullptr, nullptr, newx, 0, DD, DD);
    add_ln_k<float, bf16, bf16><<<dim3(BL), blk, 0, stream>>>(x, newx, g1, b1, x1);

    // Mamba in-projection
    mfma_gemm128_k<bf16><<<dim3(2*DIN/128, BL/128, 1), blk, 0, stream>>>(
        x1, DD, Wint, 0, DD, nullptr, nullptr, nullptr, xz, 0, 2*DIN, DD);

    // Depthwise conv + SiLU
    conv_silu_k<<<dim3(BL*DIN/256), blk, 0, stream>>>(xz, cw, cb, xc);

    // dbl = xc @ Wx (f32 out, N=64 -> small-tile GEMM)
    mfma_gemm_k<float><<<dim3(64/64, BL/64), blk, 0, stream>>>(xc, DIN, Wxt, DIN, nullptr, dbl, 64, DIN);

    // dt = softplus(dbl[:, :32] @ Wdt + bdt)  (softplus fused in epilogue)
    gemm_k<float, bf16, true><<<dim3(DIN/32, BL/32), blk, 0, stream>>>(dbl, 64, Wdt, DIN, bdt, dtb, DIN, BL, DIN, RR);

    // Chunked selective scan (3 phases) + skip + gate (y -> xi half of xz)
    scan_p1_k<<<dim3((DIN/256)*CC, BB), blk, 0, stream>>>(dtb, xc, dbl, Alog, Pp, Sp);
    scan_p2_k<<<dim3(BDN/256), blk, 0, stream>>>(Pp, Sp, Hc);
    scan_p3_k<<<dim3((DIN/256)*CC, BB), blk, 0, stream>>>(dtb, xc, dbl, Alog, Dv, Hc, xz);

    // Mamba out-projection
    mfma_gemm128_k<bf16><<<dim3(DD/128, BL/128, 1), blk, 0, stream>>>(
        xz, 2*DIN, Woutt, 0, DIN, nullptr, nullptr, nullptr, ym, 0, DD, DIN);

    // Final residual LN -> f32 out
    add_ln_k<bf16, bf16, float><<<dim3(BL), blk, 0, stream>>>(x1, ym, g2, b2, out);
}

// Round 21
// 518.623 us; speedup vs baseline: 1.3131x; 1.0007x over previous
//
#include <hip/hip_runtime.h>
#include <hip/hip_bf16.h>

// Problem constants (B=4, L=1024, D=512, H=8, E=64, DIN=1024, N=16, K=4, R=32)
#define BB 4
#define LL 1024
#define DD 512
#define HH 8
#define EE 64
#define DIN 1024
#define NN 16
#define KK 4
#define RR 32
#define BL (BB*LL)   // 4096 rows
#define CC 32        // scan chunks (32 -> LC=32, 2048 waves in p1/p3)
#define LC (LL/CC)   // 32 steps per chunk
#define BDN (BB*DIN*NN)   // 65536 independent recurrences

using bf16 = __hip_bfloat16;
typedef __attribute__((ext_vector_type(8))) short short8;   // 8 bf16 = 4 VGPRs
typedef __attribute__((ext_vector_type(4))) float f32x4;

__device__ __forceinline__ float ldf(const float* p) { return *p; }
__device__ __forceinline__ float ldf(const bf16* p) { return __bfloat162float(*p); }
__device__ __forceinline__ void stf(float* p, float v) { *p = v; }
__device__ __forceinline__ void stf(bf16* p, float v) { *p = __float2bfloat16(v); }
__device__ __forceinline__ short f2bs(float f) { bf16 h = __float2bfloat16(f); return *(short*)&h; }

// ---------------------------------------------------------------------------
// Batched weight transpose + f32->bf16 convert tail, one launch.
// ---------------------------------------------------------------------------
struct TpwJob { const float* in; bf16* out; int Kd, Nd, gx, tile0; };
struct TpwJobs { TpwJob j[8]; };

__global__ void tpw_batch_k(TpwJobs jobs, int tile_total,
                            const float* __restrict__ cvt_in,
                            bf16* __restrict__ cvt_out, int cvt_n)
{
    const int tile = blockIdx.x;
    if (tile >= tile_total) {
        int i = (tile - tile_total) * 256 + threadIdx.x;
        if (i < cvt_n) cvt_out[i] = __float2bfloat16(cvt_in[i]);
        return;
    }
    int ji = 0;
#pragma unroll
    for (int i = 1; i < 8; ++i) if (tile >= jobs.j[i].tile0) ji = i;
    const TpwJob jb = jobs.j[ji];
    const int lt = tile - jb.tile0;
    const int n0 = (lt % jb.gx) * 32;
    const int k0 = (lt / jb.gx) * 32;

    __shared__ float t[32][33];
    const int tx = threadIdx.x & 31, ty = threadIdx.x >> 5;
#pragma unroll
    for (int i = 0; i < 4; ++i)
        t[ty + 8 * i][tx] = jb.in[(size_t)(k0 + ty + 8 * i) * jb.Nd + n0 + tx];
    __syncthreads();
#pragma unroll
    for (int i = 0; i < 4; ++i)
        jb.out[(size_t)(n0 + ty + 8 * i) * jb.Kd + k0 + tx] = __float2bfloat16(t[tx][ty + 8 * i]);
}

// ---------------------------------------------------------------------------
// V transpose per head: vT[bh][e][l] = v[b][l][h*64+e]
// ---------------------------------------------------------------------------
__global__ void tpv_k(const bf16* __restrict__ v, bf16* __restrict__ vT)
{
    __shared__ float t[32][33];
    const int l0 = blockIdx.x * 32;
    const int e0 = blockIdx.y * 32;
    const int bh = blockIdx.z, b = bh >> 3, h = bh & 7;
    const int tx = threadIdx.x & 31, ty = threadIdx.x >> 5;
#pragma unroll
    for (int i = 0; i < 4; ++i)
        t[ty + 8 * i][tx] = ldf(&v[(size_t)(b * LL + l0 + ty + 8 * i) * DD + h * EE + e0 + tx]);
    __syncthreads();
#pragma unroll
    for (int i = 0; i < 4; ++i)
        stf(&vT[(size_t)(bh * EE + e0 + ty + 8 * i) * LL + l0 + tx], t[tx][ty + 8 * i]);
}

// ---------------------------------------------------------------------------
// Big MFMA GEMM: 128x128 block tile, 4 waves 2x2, 64x64 per wave (acc[4][4]).
// Optional z-batching. Grid (N/128, M/128, nz).
// ---------------------------------------------------------------------------
template <typename TC>
__global__ void mfma_gemm128_k(const bf16* __restrict__ A, int lda,
                               const bf16* __restrict__ Bt0, size_t bstride, int ldb,
                               const float* __restrict__ bias0,
                               const float* __restrict__ bias1,
                               const float* __restrict__ bias2,
                               TC* __restrict__ C0, size_t cstride, int ldc, int Kd)
{
    const int z = blockIdx.z;
    const bf16* Bt = Bt0 + (size_t)z * bstride;
    TC* C = C0 + (size_t)z * cstride;
    const float* bias = (z == 0) ? bias0 : (z == 1) ? bias1 : bias2;

    const int lane = threadIdx.x & 63;
    const int w = threadIdx.x >> 6;
    const int m = lane & 15, quad = lane >> 4;
    const int m0 = blockIdx.y * 128 + (w >> 1) * 64;
    const int n0 = blockIdx.x * 128 + (w & 1) * 64;

    f32x4 acc[4][4] = {};
    const bf16* ap = A + (size_t)(m0 + m) * lda + quad * 8;
    const bf16* bp = Bt + (size_t)(n0 + m) * ldb + quad * 8;
    const size_t rsa = (size_t)16 * lda;
    const size_t rsb = (size_t)16 * ldb;
    for (int k = 0; k < Kd; k += 32) {
        short8 a[4], b[4];
#pragma unroll
        for (int i = 0; i < 4; ++i) a[i] = *(const short8*)(ap + i * rsa + k);
#pragma unroll
        for (int j = 0; j < 4; ++j) b[j] = *(const short8*)(bp + j * rsb + k);
#pragma unroll
        for (int i = 0; i < 4; ++i)
#pragma unroll
            for (int j = 0; j < 4; ++j)
                acc[i][j] = __builtin_amdgcn_mfma_f32_16x16x32_bf16(a[i], b[j], acc[i][j], 0, 0, 0);
    }
    float bv[4];
#pragma unroll
    for (int j = 0; j < 4; ++j) bv[j] = bias ? bias[n0 + j * 16 + m] : 0.f;
#pragma unroll
    for (int i = 0; i < 4; ++i)
#pragma unroll
        for (int j = 0; j < 4; ++j)
#pragma unroll
            for (int r = 0; r < 4; ++r) {
                int row = m0 + i * 16 + quad * 4 + r;
                int col = n0 + j * 16 + m;
                stf(&C[(size_t)row * ldc + col], acc[i][j][r] + bv[j]);
            }
}

// ---------------------------------------------------------------------------
// MFMA GEMM (small-N variant, 64x64 block): kept for the Wx GEMM (N=64).
// ---------------------------------------------------------------------------
template <typename TC>
__global__ void mfma_gemm_k(const bf16* __restrict__ A, int lda,
                            const bf16* __restrict__ Bt, int ldb,
                            const float* __restrict__ bias,
                            TC* __restrict__ C, int ldc, int Kd)
{
    const int lane = threadIdx.x & 63;
    const int w = threadIdx.x >> 6;
    const int m = lane & 15, quad = lane >> 4;
    const int m0 = blockIdx.y * 64 + (w >> 1) * 32;
    const int n0 = blockIdx.x * 64 + (w & 1) * 32;
    f32x4 acc[2][2] = {};
    const bf16* a0p = A + (size_t)(m0 + m) * lda + quad * 8;
    const bf16* a1p = a0p + (size_t)16 * lda;
    const bf16* b0p = Bt + (size_t)(n0 + m) * ldb + quad * 8;
    const bf16* b1p = b0p + (size_t)16 * ldb;
    for (int k = 0; k < Kd; k += 32) {
        short8 a0 = *(const short8*)(a0p + k);
        short8 a1 = *(const short8*)(a1p + k);
        short8 b0 = *(const short8*)(b0p + k);
        short8 b1 = *(const short8*)(b1p + k);
        acc[0][0] = __builtin_amdgcn_mfma_f32_16x16x32_bf16(a0, b0, acc[0][0], 0, 0, 0);
        acc[0][1] = __builtin_amdgcn_mfma_f32_16x16x32_bf16(a0, b1, acc[0][1], 0, 0, 0);
        acc[1][0] = __builtin_amdgcn_mfma_f32_16x16x32_bf16(a1, b0, acc[1][0], 0, 0, 0);
        acc[1][1] = __builtin_amdgcn_mfma_f32_16x16x32_bf16(a1, b1, acc[1][1], 0, 0, 0);
    }
#pragma unroll
    for (int i = 0; i < 2; ++i)
#pragma unroll
        for (int j = 0; j < 2; ++j)
#pragma unroll
            for (int r = 0; r < 4; ++r) {
                int row = m0 + i * 16 + quad * 4 + r;
                int col = n0 + j * 16 + (lane & 15);
                float vv = acc[i][j][r] + (bias ? bias[col] : 0.f);
                stf(&C[(size_t)row * ldc + col], vv);
            }
}

// ---------------------------------------------------------------------------
// dt = softplus(dbl[:, :32] @ Wdt + bdt) via MFMA. K=32 = one 16x16x32 step.
// A = dbl f32 [BL][64] cols 0..31 (converted to bf16 inline); B = Wdtt bf16
// [DIN][32]. 128x128 block tile, 4 waves 2x2. Grid (DIN/128, BL/128).
// ---------------------------------------------------------------------------
__global__ void dt_mfma_k(const float* __restrict__ dbl,
                          const bf16* __restrict__ Wdtt,
                          const float* __restrict__ bdt,
                          bf16* __restrict__ dtb)
{
    const int lane = threadIdx.x & 63;
    const int w = threadIdx.x >> 6;
    const int m = lane & 15, quad = lane >> 4;
    const int m0 = blockIdx.y * 128 + (w >> 1) * 64;
    const int n0 = blockIdx.x * 128 + (w & 1) * 64;

    short8 a[4], b[4];
#pragma unroll
    for (int i = 0; i < 4; ++i) {
        const float* ap = dbl + (size_t)(m0 + i * 16 + m) * 64 + quad * 8;
        f32x4 lo = *(const f32x4*)ap;
        f32x4 hi = *(const f32x4*)(ap + 4);
        a[i][0] = f2bs(lo[0]); a[i][1] = f2bs(lo[1]); a[i][2] = f2bs(lo[2]); a[i][3] = f2bs(lo[3]);
        a[i][4] = f2bs(hi[0]); a[i][5] = f2bs(hi[1]); a[i][6] = f2bs(hi[2]); a[i][7] = f2bs(hi[3]);
    }
#pragma unroll
    for (int j = 0; j < 4; ++j)
        b[j] = *(const short8*)(Wdtt + (size_t)(n0 + j * 16 + m) * 32 + quad * 8);

    f32x4 acc[4][4] = {};
#pragma unroll
    for (int i = 0; i < 4; ++i)
#pragma unroll
        for (int j = 0; j < 4; ++j)
            acc[i][j] = __builtin_amdgcn_mfma_f32_16x16x32_bf16(a[i], b[j], acc[i][j], 0, 0, 0);

    float bv[4];
#pragma unroll
    for (int j = 0; j < 4; ++j) bv[j] = bdt[n0 + j * 16 + m];
#pragma unroll
    for (int i = 0; i < 4; ++i)
#pragma unroll
        for (int j = 0; j < 4; ++j)
#pragma unroll
            for (int r = 0; r < 4; ++r) {
                int row = m0 + i * 16 + quad * 4 + r;
                int col = n0 + j * 16 + m;
                float v = acc[i][j][r] + bv[j];
                v = (v > 20.f) ? v : log1pf(__expf(v));
                stf(&dtb[(size_t)row * DIN + col], v);
            }
}

// ---------------------------------------------------------------------------
// FUSED attention v5: scores + online softmax + (attn@V).
// Sector-contiguous f32x4 NT stores; online softmax; halved P tile.
// ---------------------------------------------------------------------------
__global__ void attn_fused_k(const bf16* __restrict__ q, const bf16* __restrict__ k,
                             const bf16* __restrict__ vT,
                             float* __restrict__ attn, bf16* __restrict__ o)
{
    const int n = blockIdx.x;
    const int bh = ((n >> 9) << 3) | (n & 7);
    const int rt = (n >> 3) & 63;
    const int b = bh >> 3, h = bh & 7;
    const int w = threadIdx.x >> 6;
    const int lane = threadIdx.x & 63;
    const int m = lane & 15, quad = lane >> 4;
    __shared__ float pm[4][16], ps[4][16];
    __shared__ bf16 P[16][524];   // half-tile: 16 rows x 512 cols, stride 524

    const bf16* qp = q + (size_t)(b * LL + rt * 16 + m) * DD + h * EE + quad * 8;
    short8 a0 = *(const short8*)(qp);
    short8 a1 = *(const short8*)(qp + 32);

    f32x4 acc[16];
#pragma unroll
    for (int t = 0; t < 16; ++t) {
        int srow = w * 256 + (t >> 2) * 64 + m * 4 + (t & 3);
        const bf16* kp = k + (size_t)(b * LL + srow) * DD + h * EE + quad * 8;
        short8 b0 = *(const short8*)(kp);
        short8 b1 = *(const short8*)(kp + 32);
        f32x4 c = {};
        c = __builtin_amdgcn_mfma_f32_16x16x32_bf16(a0, b0, c, 0, 0, 0);
        c = __builtin_amdgcn_mfma_f32_16x16x32_bf16(a1, b1, c, 0, 0, 0);
        acc[t] = c;
    }

#pragma unroll
    for (int r = 0; r < 4; ++r) {
        float mx = -1e30f;
#pragma unroll
        for (int t = 0; t < 16; ++t) { acc[t][r] *= 0.125f; mx = fmaxf(mx, acc[t][r]); }
        mx = fmaxf(mx, __shfl_xor(mx, 1)); mx = fmaxf(mx, __shfl_xor(mx, 2));
        mx = fmaxf(mx, __shfl_xor(mx, 4)); mx = fmaxf(mx, __shfl_xor(mx, 8));
        float s = 0.f;
#pragma unroll
        for (int t = 0; t < 16; ++t) { float e = __expf(acc[t][r] - mx); acc[t][r] = e; s += e; }
        s += __shfl_xor(s, 1); s += __shfl_xor(s, 2);
        s += __shfl_xor(s, 4); s += __shfl_xor(s, 8);
        if (m == 0) { pm[w][quad * 4 + r] = mx; ps[w][quad * 4 + r] = s; }
    }
    __syncthreads();

    float sc[4];
#pragma unroll
    for (int r = 0; r < 4; ++r) {
        const int row = quad * 4 + r;
        float m0 = pm[0][row], m1 = pm[1][row], m2 = pm[2][row], m3 = pm[3][row];
        float M = fmaxf(fmaxf(m0, m1), fmaxf(m2, m3));
        float e0 = __expf(m0 - M), e1 = __expf(m1 - M), e2 = __expf(m2 - M), e3 = __expf(m3 - M);
        float T = ps[0][row] * e0 + ps[1][row] * e1 + ps[2][row] * e2 + ps[3][row] * e3;
        float ew = (w == 0) ? e0 : (w == 1) ? e1 : (w == 2) ? e2 : e3;
        sc[r] = ew / T;
    }
#pragma unroll
    for (int r = 0; r < 4; ++r) {
        const int row = quad * 4 + r;
        float* op = attn + ((size_t)bh * LL + rt * 16 + row) * LL + w * 256;
#pragma unroll
        for (int g = 0; g < 4; ++g) {
            f32x4 pv;
            pv[0] = acc[4 * g + 0][r] * sc[r];
            pv[1] = acc[4 * g + 1][r] * sc[r];
            pv[2] = acc[4 * g + 2][r] * sc[r];
            pv[3] = acc[4 * g + 3][r] * sc[r];
            __builtin_nontemporal_store(pv, (f32x4*)(op + g * 64) + m);
            if (w < 2) {
                bf16* pp = &P[row][(w & 1) * 256 + g * 64 + m * 4];
                pp[0] = __float2bfloat16(pv[0]);
                pp[1] = __float2bfloat16(pv[1]);
                pp[2] = __float2bfloat16(pv[2]);
                pp[3] = __float2bfloat16(pv[3]);
            }
        }
    }
    __syncthreads();   // P half-0 ready

    const bf16* vp = vT + (size_t)(bh * EE + w * 16 + m) * LL + quad * 8;
    f32x4 oacc = {};
    for (int k0 = 0; k0 < 512; k0 += 32) {
        short8 af = *(const short8*)(&P[m][k0 + quad * 8]);
        short8 bf = *(const short8*)(vp + k0);
        oacc = __builtin_amdgcn_mfma_f32_16x16x32_bf16(af, bf, oacc, 0, 0, 0);
    }
    __syncthreads();   // everyone done reading half-0
    if (w >= 2) {
#pragma unroll
        for (int r = 0; r < 4; ++r) {
            const int row = quad * 4 + r;
#pragma unroll
            for (int g = 0; g < 4; ++g) {
                bf16* pp = &P[row][(w & 1) * 256 + g * 64 + m * 4];
                pp[0] = __float2bfloat16(acc[4 * g + 0][r] * sc[r]);
                pp[1] = __float2bfloat16(acc[4 * g + 1][r] * sc[r]);
                pp[2] = __float2bfloat16(acc[4 * g + 2][r] * sc[r]);
                pp[3] = __float2bfloat16(acc[4 * g + 3][r] * sc[r]);
            }
        }
    }
    __syncthreads();   // P half-1 ready
    for (int k0 = 512; k0 < 1024; k0 += 32) {
        short8 af = *(const short8*)(&P[m][k0 - 512 + quad * 8]);
        short8 bf = *(const short8*)(vp + k0);
        oacc = __builtin_amdgcn_mfma_f32_16x16x32_bf16(af, bf, oacc, 0, 0, 0);
    }
#pragma unroll
    for (int r = 0; r < 4; ++r) {
        int row = rt * 16 + quad * 4 + r;
        stf(&o[(size_t)(b * LL + row) * DD + h * EE + w * 16 + m], oacc[r]);
    }
}

// ---------------------------------------------------------------------------
// out = LayerNorm(a + r) * g + beta.  One block (256 thr) per row of 512.
// ---------------------------------------------------------------------------
template <typename TA, typename TR, typename TO>
__global__ void add_ln_k(const TA* __restrict__ a, const TR* __restrict__ r,
                         const float* __restrict__ g, const float* __restrict__ be,
                         TO* __restrict__ out)
{
    const int row = blockIdx.x;
    const int tid = threadIdx.x;
    __shared__ float red[256];
    const size_t base = (size_t)row * DD;
    float v0 = ldf(&a[base + tid]) + ldf(&r[base + tid]);
    float v1 = ldf(&a[base + 256 + tid]) + ldf(&r[base + 256 + tid]);
    red[tid] = v0 + v1;
    __syncthreads();
    for (int off = 128; off > 0; off >>= 1) {
        if (tid < off) red[tid] += red[tid + off];
        __syncthreads();
    }
    const float mu = red[0] * (1.f / 512.f);
    __syncthreads();
    float d0 = v0 - mu, d1 = v1 - mu;
    red[tid] = d0 * d0 + d1 * d1;
    __syncthreads();
    for (int off = 128; off > 0; off >>= 1) {
        if (tid < off) red[tid] += red[tid + off];
        __syncthreads();
    }
    const float rs = rsqrtf(red[0] * (1.f / 512.f) + 1e-5f);
    stf(&out[base + tid], d0 * rs * g[tid] + be[tid]);
    stf(&out[base + 256 + tid], d1 * rs * g[tid + 256] + be[tid + 256]);
}

// ---------------------------------------------------------------------------
// Depthwise causal conv (K=4) + bias + SiLU.
// ---------------------------------------------------------------------------
__global__ void conv_silu_k(const bf16* __restrict__ xz,
                            const float* __restrict__ w,
                            const float* __restrict__ cb,
                            bf16* __restrict__ xc)
{
    const int idx = blockIdx.x * 256 + threadIdx.x;
    const int c = idx & (DIN - 1);
    const int t = (idx >> 10) & (LL - 1);
    const int b = idx >> 20;
    float acc = cb[c];
    const bf16* xi = xz + (size_t)b * LL * (2 * DIN) + c;
#pragma unroll
    for (int j = 0; j < KK; ++j) {
        int tt = t - (KK - 1) + j;
        if (tt >= 0) acc += w[c * KK + j] * ldf(&xi[(size_t)tt * (2 * DIN)]);
    }
    stf(&xc[idx], acc / (1.f + __expf(-acc)));
}

// ---------------------------------------------------------------------------
// Chunked selective scan, phase 1 (n-in-register).
// ---------------------------------------------------------------------------
__global__ void scan_p1_k(const bf16* __restrict__ dt, const bf16* __restrict__ xc,
                          const float* __restrict__ dbl, const float* __restrict__ Alog,
                          float* __restrict__ P, float* __restrict__ S)
{
    const int d = (blockIdx.x & 3) * 256 + threadIdx.x;   // DIN/256 = 4
    const int c = blockIdx.x >> 2;
    const int b = blockIdx.y;
    float A[NN];
#pragma unroll
    for (int n = 0; n < NN; ++n) A[n] = -__expf(Alog[d * NN + n]);
    const int t0 = c * LC;
    const bf16* dt_b = dt + ((size_t)b * LL + t0) * DIN + d;
    const bf16* xc_b = xc + ((size_t)b * LL + t0) * DIN + d;
    const float* dbl_b = dbl + ((size_t)b * LL + t0) * 64 + RR;   // uniform per wave
    float h[NN];
#pragma unroll
    for (int n = 0; n < NN; ++n) h[n] = 0.f;
    float sdt = 0.f;
#pragma unroll 4
    for (int t = 0; t < LC; ++t) {
        float dtv = ldf(&dt_b[(size_t)t * DIN]);
        float xcv = ldf(&xc_b[(size_t)t * DIN]);
        float dtx = dtv * xcv;
        sdt += dtv;
#pragma unroll
        for (int n = 0; n < NN; ++n) {
            float dA = __expf(dtv * A[n]);
            h[n] = h[n] * dA + dtx * dbl_b[(size_t)t * 64 + n];
        }
    }
    float* Pp = P + (size_t)c * BDN + ((size_t)(b * DIN + d)) * NN;
    float* Sp = S + (size_t)c * BDN + ((size_t)(b * DIN + d)) * NN;
#pragma unroll
    for (int n = 0; n < NN; ++n) { Pp[n] = __expf(sdt * A[n]); Sp[n] = h[n]; }
}

// ---------------------------------------------------------------------------
// Phase 2: serial carry scan over the CC chunks. One thread per bdn.
// ---------------------------------------------------------------------------
__global__ void scan_p2_k(const float* __restrict__ P, const float* __restrict__ S,
                          float* __restrict__ Hc)
{
    const size_t bdn = (size_t)blockIdx.x * 256 + threadIdx.x;
    float h = 0.f;
#pragma unroll
    for (int c = 0; c < CC; ++c) {
        Hc[(size_t)c * BDN + bdn] = h;
        h = S[(size_t)c * BDN + bdn] + P[(size_t)c * BDN + bdn] * h;
    }
}

// ---------------------------------------------------------------------------
// Phase 3 (n-in-register): replay each chunk from its carry-in.
// ---------------------------------------------------------------------------
__global__ void scan_p3_k(const bf16* __restrict__ dt, const bf16* __restrict__ xc,
                          const float* __restrict__ dbl, const float* __restrict__ Alog,
                          const float* __restrict__ Dv, const float* __restrict__ Hc,
                          bf16* __restrict__ xzm)
{
    const int d = (blockIdx.x & 3) * 256 + threadIdx.x;
    const int c = blockIdx.x >> 2;
    const int b = blockIdx.y;
    float A[NN];
#pragma unroll
    for (int n = 0; n < NN; ++n) A[n] = -__expf(Alog[d * NN + n]);
    const float Dp = Dv[d];
    const int t0 = c * LC;
    const bf16* dt_b = dt + ((size_t)b * LL + t0) * DIN + d;
    const bf16* xc_b = xc + ((size_t)b * LL + t0) * DIN + d;
    const float* dbl_b = dbl + ((size_t)b * LL + t0) * 64 + RR;   // uniform per wave
    bf16* xz_b = xzm + ((size_t)b * LL + t0) * (2 * DIN);
    const float* hp = Hc + (size_t)c * BDN + ((size_t)(b * DIN + d)) * NN;
    float h[NN];
#pragma unroll
    for (int n = 0; n < NN; ++n) h[n] = hp[n];
#pragma unroll 2
    for (int t = 0; t < LC; ++t) {
        float dtv = ldf(&dt_b[(size_t)t * DIN]);
        float xcv = ldf(&xc_b[(size_t)t * DIN]);
        float dtx = dtv * xcv;
        float y = 0.f;
#pragma unroll
        for (int n = 0; n < NN; ++n) {
            float dA = __expf(dtv * A[n]);
            h[n] = h[n] * dA + dtx * dbl_b[(size_t)t * 64 + n];
            y += h[n] * dbl_b[(size_t)t * 64 + NN + n];
        }
        float zv = ldf(&xz_b[(size_t)t * (2 * DIN) + DIN + d]);
        float yv = y + xcv * Dp;
        yv *= zv / (1.f + __expf(-zv));
        stf(&xz_b[(size_t)t * (2 * DIN) + d], yv);
    }
}

// ---------------------------------------------------------------------------
extern "C" void kernel_launch(void* const* d_in, const int* in_sizes, int n_in,
                              void* d_out, int out_size, void* d_ws, size_t ws_size,
                              hipStream_t stream)
{
    const float* x    = (const float*)d_in[0];
    const float* Wq   = (const float*)d_in[1];
    const float* bq   = (const float*)d_in[2];
    const float* Wk   = (const float*)d_in[3];
    const float* bk   = (const float*)d_in[4];
    const float* Wv   = (const float*)d_in[5];
    const float* bv   = (const float*)d_in[6];
    const float* Wo   = (const float*)d_in[7];
    const float* bo   = (const float*)d_in[8];
    const float* g1   = (const float*)d_in[9];
    const float* b1   = (const float*)d_in[10];
    const float* g2   = (const float*)d_in[11];
    const float* b2   = (const float*)d_in[12];
    const float* Win  = (const float*)d_in[13];
    const float* cw   = (const float*)d_in[14];
    const float* cb   = (const float*)d_in[15];
    const float* Wx   = (const float*)d_in[16];
    const float* Wdt  = (const float*)d_in[17];
    const float* bdt  = (const float*)d_in[18];
    const float* Alog = (const float*)d_in[19];
    const float* Dv   = (const float*)d_in[20];
    const float* Wout = (const float*)d_in[21];

    float* out  = (float*)d_out;                     // (B,L,D) f32
    float* attn = out + (size_t)BL * DD;             // (B,H,L,L) f32

    const size_t M1 = 1048576;
    bf16* wsb = (bf16*)d_ws;
    bf16* xb   = wsb;                 // 2M bf16 [0,4MB)   (dead after QKV gemms)
    bf16* q    = wsb + 2*M1;          // 2M [4,8MB)  (newx; dead after LN1)
    bf16* kb   = wsb + 4*M1;          // 2M [8,12MB) (dead after attn)
    bf16* v    = wsb + 6*M1;          // 2M [12,16MB) (dead after tpv; reused as ym late)
    bf16* o    = wsb + 8*M1;          // 2M (dead after Wo gemm)
    bf16* x1   = wsb + 10*M1;         // 2M (LIVE through final LN)
    bf16* xz   = wsb + 12*M1;         // 8M
    bf16* xc   = wsb + 20*M1;         // 4M
    bf16* dtb  = wsb + 24*M1;         // 4M
    float* dbl = (float*)(wsb + 28*M1);          // 262144 f32
    bf16* vT   = wsb + 28*M1 + 524288;           // 2M [~59.8MB, +4MB)
    bf16* Wqt  = vT + 2*M1;
    bf16* Wkt  = Wqt + 262144;
    bf16* Wvt  = Wkt + 262144;
    bf16* Wot  = Wvt + 262144;
    bf16* Wint = Wot + 262144;        // 2048x512 = 1M
    bf16* Wxt  = Wint + M1;           // 64x1024
    bf16* Woutt= Wxt + 65536;         // 512x1024
    bf16* Wdtt = Woutt + 524288;      // 1024x32 = 32768   (end ~69.4 MB)
    bf16* newx = q;
    bf16* ym   = v;
    // Scan scratch (CC=32 -> 8MB each), aliased onto regions dead at scan time:
    float* Pp = (float*)xb;    // spans xb+q   [0, 8MB)
    float* Sp = (float*)kb;    // spans kb+v   [8MB, 16MB)  (ym=v written after p2 done)
    float* Hc = (float*)vT;    // spans vT..Wint (8MB exactly; Wxt/Woutt/Wdtt untouched)

    const dim3 blk(256);

    // Stage 0: batched weight transposes + x->bf16 convert, single launch
    TpwJobs tj;
    int t0 = 0, nj = 0;
    auto addjob = [&](const float* in, bf16* outp, int Kd, int Nd) {
        tj.j[nj] = {in, outp, Kd, Nd, Nd / 32, t0};
        t0 += (Nd / 32) * (Kd / 32);
        ++nj;
    };
    addjob(Wq,   Wqt,   DD,  DD);
    addjob(Wk,   Wkt,   DD,  DD);
    addjob(Wv,   Wvt,   DD,  DD);
    addjob(Wo,   Wot,   DD,  DD);
    addjob(Win,  Wint,  DD,  2*DIN);
    addjob(Wx,   Wxt,   DIN, 64);
    addjob(Wout, Woutt, DIN, DD);
    addjob(Wdt,  Wdtt,  RR,  DIN);
    tpw_batch_k<<<dim3(t0 + BL*DD/256), blk, 0, stream>>>(tj, t0, x, xb, BL*DD);

    // QKV projections fused into one launch (Wqt/Wkt/Wvt and q/kb/v contiguous)
    mfma_gemm128_k<bf16><<<dim3(DD/128, BL/128, 3), blk, 0, stream>>>(
        xb, DD, Wqt, (size_t)DD*DD, DD, bq, bk, bv, q, (size_t)2*M1, DD, DD);
    tpv_k<<<dim3(LL/32, EE/32, BB*HH), blk, 0, stream>>>(v, vT);

    // Fused attention: scores + softmax + AV (contiguous f32x4 NT attn stores)
    attn_fused_k<<<dim3((LL/16)*BB*HH), blk, 0, stream>>>(q, kb, vT, attn, o);

    // Output projection + LN1
    mfma_gemm128_k<bf16><<<dim3(DD/128, BL/128, 1), blk, 0, stream>>>(
        o, DD, Wot, 0, DD, bo, nullptr, nullptr, newx, 0, DD, DD);
    add_ln_k<float, bf16, bf16><<<dim3(BL), blk, 0, stream>>>(x, newx, g1, b1, x1);

    // Mamba in-projection
    mfma_gemm128_k<bf16><<<dim3(2*DIN/128, BL/128, 1), blk, 0, stream>>>(
        x1, DD, Wint, 0, DD, nullptr, nullptr, nullptr, xz, 0, 2*DIN, DD);

    // Depthwise conv + SiLU
    conv_silu_k<<<dim3(BL*DIN/256), blk, 0, stream>>>(xz, cw, cb, xc);

    // dbl = xc @ Wx (f32 out, N=64 -> small-tile GEMM)
    mfma_gemm_k<float><<<dim3(64/64, BL/64), blk, 0, stream>>>(xc, DIN, Wxt, DIN, nullptr, dbl, 64, DIN);

    // dt = softplus(dbl[:, :32] @ Wdt + bdt) via MFMA (K=32, one step)
    dt_mfma_k<<<dim3(DIN/128, BL/128), blk, 0, stream>>>(dbl, Wdtt, bdt, dtb);

    // Chunked selective scan (3 phases) + skip + gate (y -> xi half of xz)
    scan_p1_k<<<dim3((DIN/256)*CC, BB), blk, 0, stream>>>(dtb, xc, dbl, Alog, Pp, Sp);
    scan_p2_k<<<dim3(BDN/256), blk, 0, stream>>>(Pp, Sp, Hc);
    scan_p3_k<<<dim3((DIN/256)*CC, BB), blk, 0, stream>>>(dtb, xc, dbl, Alog, Dv, Hc, xz);

    // Mamba out-projection
    mfma_gemm128_k<bf16><<<dim3(DD/128, BL/128, 1), blk, 0, stream>>>(
        xz, 2*DIN, Woutt, 0, DIN, nullptr, nullptr, nullptr, ym, 0, DD, DIN);

    // Final residual LN -> f32 out
    add_ln_k<bf16, bf16, float><<<dim3(BL), blk, 0, stream>>>(x1, ym, g2, b2, out);
}